// Round 7
// baseline (88.463 us; speedup 1.0000x reference)
//
#include <hip/hip_runtime.h>
#include <cmath>

#define NF 4096
#define PI2F 6.2831853071795864769f

typedef float2 cf;

__device__ __forceinline__ cf cmulf(cf a, cf b){
  return make_float2(fmaf(a.x, b.x, -(a.y*b.y)), fmaf(a.x, b.y, a.y*b.x));
}
__device__ __forceinline__ cf cadd(cf a, cf b){ return make_float2(a.x+b.x, a.y+b.y); }
__device__ __forceinline__ cf csub(cf a, cf b){ return make_float2(a.x-b.x, a.y-b.y); }

// ---- k_main LDS map (radix-8 strides {512,64,8,1}): cf-granularity XOR.
// For every stage pattern the lane->bank-pair map is rank-4 linear => exact
// 4-way b64 floor, zero extra conflicts. No b128 accesses exist to break.
// LDS = 4096 cf = 32 KiB.
__device__ __forceinline__ int physX(int i){ return i ^ ((i >> 4) & 15); }
// ---- k_fftkr LDS map: pair-preserving XOR (radix-16 path, round-4 proven) ----
__device__ __forceinline__ int phys16(int i){ return i ^ (((i >> 4) & 7) << 1); }

// base-8 digit reversal of a 12-bit index (involution)
__device__ __forceinline__ int rev8(int i){
  return ((i & 7) << 9) | (((i >> 3) & 7) << 6) | (((i >> 6) & 7) << 3) | ((i >> 9) & 7);
}

// radix-8 DFT in registers; INV=0 forward (e^{-i}), INV=1 inverse (e^{+i}), unnormalized.
template<int INV>
__device__ __forceinline__ void dft8(cf* v){
  const float HF = 0.7071067811865476f;
  cf e0,e1,e2,e3,o0,o1,o2,o3;
  {
    cf t0 = cadd(v[0], v[4]);
    cf t1 = csub(v[0], v[4]);
    cf t2 = cadd(v[2], v[6]);
    cf t3 = csub(v[2], v[6]);
    e0 = cadd(t0,t2); e2 = csub(t0,t2);
    if (!INV){ e1 = make_float2(t1.x+t3.y, t1.y-t3.x); e3 = make_float2(t1.x-t3.y, t1.y+t3.x); }
    else     { e1 = make_float2(t1.x-t3.y, t1.y+t3.x); e3 = make_float2(t1.x+t3.y, t1.y-t3.x); }
  }
  {
    cf t0 = cadd(v[1], v[5]);
    cf t1 = csub(v[1], v[5]);
    cf t2 = cadd(v[3], v[7]);
    cf t3 = csub(v[3], v[7]);
    o0 = cadd(t0,t2); o2 = csub(t0,t2);
    if (!INV){ o1 = make_float2(t1.x+t3.y, t1.y-t3.x); o3 = make_float2(t1.x-t3.y, t1.y+t3.x); }
    else     { o1 = make_float2(t1.x-t3.y, t1.y+t3.x); o3 = make_float2(t1.x+t3.y, t1.y-t3.x); }
  }
  cf w1, w2, w3;
  if (!INV){
    w1 = make_float2(HF*(o1.x + o1.y), HF*(o1.y - o1.x));
    w2 = make_float2(o2.y, -o2.x);
    w3 = make_float2(HF*(o3.y - o3.x), -HF*(o3.x + o3.y));
  } else {
    w1 = make_float2(HF*(o1.x - o1.y), HF*(o1.y + o1.x));
    w2 = make_float2(-o2.y, o2.x);
    w3 = make_float2(-HF*(o3.x + o3.y), HF*(o3.x - o3.y));
  }
  v[0] = cadd(e0,o0); v[4] = csub(e0,o0);
  v[1] = cadd(e1,w1); v[5] = csub(e1,w1);
  v[2] = cadd(e2,w2); v[6] = csub(e2,w2);
  v[3] = cadd(e3,w3); v[7] = csub(e3,w3);
}

// radix-16 DFT in registers (k_fftkr path)
template<int INV>
__device__ __forceinline__ void dft16(cf* v){
  const float C1 = 0.9238795325112867f;
  const float S1 = 0.3826834323650898f;
  const float HF = 0.7071067811865476f;
  cf c[16];
#pragma unroll
  for (int q1 = 0; q1 < 4; ++q1){
    cf a = v[q1], b = v[q1+4], d = v[q1+8], e = v[q1+12];
    cf t0 = make_float2(a.x+d.x, a.y+d.y);
    cf t1 = make_float2(a.x-d.x, a.y-d.y);
    cf t2 = make_float2(b.x+e.x, b.y+e.y);
    cf t3 = make_float2(b.x-e.x, b.y-e.y);
    c[q1*4+0] = make_float2(t0.x+t2.x, t0.y+t2.y);
    c[q1*4+2] = make_float2(t0.x-t2.x, t0.y-t2.y);
    if (!INV){
      c[q1*4+1] = make_float2(t1.x+t3.y, t1.y-t3.x);
      c[q1*4+3] = make_float2(t1.x-t3.y, t1.y+t3.x);
    } else {
      c[q1*4+1] = make_float2(t1.x-t3.y, t1.y+t3.x);
      c[q1*4+3] = make_float2(t1.x+t3.y, t1.y-t3.x);
    }
  }
  {
    auto tw = [&](int i, float wr, float wi){
      float wii = INV ? -wi : wi;
      cf z = c[i];
      c[i] = make_float2(fmaf(z.x, wr, -(z.y*wii)), fmaf(z.x, wii, z.y*wr));
    };
    tw(5,  C1, -S1);
    tw(6,  HF, -HF);
    tw(7,  S1, -C1);
    tw(9,  HF, -HF);
    tw(11,-HF, -HF);
    tw(13, S1, -C1);
    tw(14,-HF, -HF);
    tw(15,-C1,  S1);
    cf z = c[10];
    c[10] = INV ? make_float2(-z.y, z.x) : make_float2(z.y, -z.x);
  }
#pragma unroll
  for (int r0 = 0; r0 < 4; ++r0){
    cf a = c[r0], b = c[4+r0], d = c[8+r0], e = c[12+r0];
    cf t0 = make_float2(a.x+d.x, a.y+d.y);
    cf t1 = make_float2(a.x-d.x, a.y-d.y);
    cf t2 = make_float2(b.x+e.x, b.y+e.y);
    cf t3 = make_float2(b.x-e.x, b.y-e.y);
    v[r0+0] = make_float2(t0.x+t2.x, t0.y+t2.y);
    v[r0+8] = make_float2(t0.x-t2.x, t0.y-t2.y);
    if (!INV){
      v[r0+4]  = make_float2(t1.x+t3.y, t1.y-t3.x);
      v[r0+12] = make_float2(t1.x-t3.y, t1.y+t3.x);
    } else {
      v[r0+4]  = make_float2(t1.x-t3.y, t1.y+t3.x);
      v[r0+12] = make_float2(t1.x+t3.y, t1.y-t3.x);
    }
  }
}

// v[r] *= e^{i*ang*r}, r=1..7. Chebyshev power build: T_{r+1} = 2c*T_r - T_{r-1}
__device__ __forceinline__ void twiddle8(cf* v, float ang){
  float s, c;
  __sincosf(ang, &s, &c);
  float c2 = 2.0f * c;
  cf T[8];
  T[1] = make_float2(c, s);
  T[2] = make_float2(fmaf(c2, c, -1.0f), c2 * s);
#pragma unroll
  for (int r = 3; r < 8; ++r)
    T[r] = make_float2(fmaf(c2, T[r-1].x, -T[r-2].x), fmaf(c2, T[r-1].y, -T[r-2].y));
#pragma unroll
  for (int r = 1; r < 8; ++r) v[r] = cmulf(v[r], T[r]);
}

// v[r] *= e^{i*ang*r}, r=1..15 (radix-16 path), Chebyshev build
__device__ __forceinline__ void twiddle16(cf* v, float ang){
  float s, c;
  __sincosf(ang, &s, &c);
  float c2 = 2.0f * c;
  cf T[16];
  T[1] = make_float2(c, s);
  T[2] = make_float2(fmaf(c2, c, -1.0f), c2 * s);
#pragma unroll
  for (int r = 3; r < 16; ++r)
    T[r] = make_float2(fmaf(c2, T[r-1].x, -T[r-2].x), fmaf(c2, T[r-1].y, -T[r-2].y));
#pragma unroll
  for (int r = 1; r < 16; ++r) v[r] = cmulf(v[r], T[r]);
}

__device__ __forceinline__ float fast_tanh(float x){
  float e = __expf(2.0f*x);
  return 1.0f - __fdividef(2.0f, e + 1.0f);
}

// ---------------- vandermonde: vand[p][l] = lambda_p^l (polar, f64 phase) -------------
__global__ void k_vand(const float* __restrict__ Lam, cf* __restrict__ vand){
  int gid = blockIdx.x*256 + threadIdx.x;        // 64*4096
  int p = gid >> 12;
  int l = gid & 4095;
  float lr = Lam[2*p], li = Lam[2*p+1];
  double r2 = (double)lr*(double)lr + (double)li*(double)li;
  double lg = 0.5 * log2(r2);                    // log2|lambda|
  double tt = atan2((double)li, (double)lr) * 0.15915494309189535; // turns
  double dl = (double)l;
  float mag = exp2f((float)(dl * lg));
  double ph = dl * tt;
  ph -= floor(ph);                               // frac turns in [0,1)
  float s, c;
  sincospif((float)(2.0*ph), &s, &c);
  vand[gid] = make_float2(mag*c, mag*s);
}

// ---------------- Kr[h][l] = Re( sum_p C[h,p]*B[p,h] * vand[p][l] ) -------------------
__global__ __launch_bounds__(512,4) void k_kr(
    const float* __restrict__ C, const float* __restrict__ Bb,
    const cf* __restrict__ vand, float* __restrict__ Kr){
  __shared__ cf Wsh[8][64];
  __shared__ cf Vt[16][512];     // 64 KiB tile
  const int t = threadIdx.x;
  const int hg = blockIdx.x >> 3;      // 32 h-groups of 8
  const int ls = blockIdx.x & 7;       // 8 l-slices of 512
  const int h0 = hg*8;
  const int l0 = ls*512;
  {
    int hl = t >> 6, p = t & 63;       // 512 entries
    int h = h0 + hl;
    cf cc = ((const cf*)C)[h*64 + p];
    cf bb = ((const cf*)Bb)[p*256 + h];
    Wsh[hl][p] = cmulf(cc, bb);
  }
  float acc[8] = {0,0,0,0,0,0,0,0};
  const int hl = t >> 6;               // wave id == local h
  const int lane = t & 63;
  for (int pc = 0; pc < 4; ++pc){
    __syncthreads();
    const float4* src = (const float4*)vand;  // row stride 2048 float4
#pragma unroll
    for (int j = 0; j < 8; ++j){
      int li = j*512 + t;              // 0..4095 float4s of tile
      int rp = li >> 8;                // tile row 0..15
      int colf4 = li & 255;
      ((float4*)Vt)[li] = src[(size_t)(pc*16 + rp)*2048 + (l0 >> 1) + colf4];
    }
    __syncthreads();
#pragma unroll
    for (int p = 0; p < 16; ++p){
      cf w = Wsh[hl][pc*16 + p];
#pragma unroll
      for (int j = 0; j < 8; ++j){
        cf vv = Vt[p][lane + 64*j];
        acc[j] = fmaf(w.x, vv.x, fmaf(-w.y, vv.y, acc[j]));
      }
    }
  }
  float* dst = Kr + (size_t)(h0 + hl)*NF + l0;
#pragma unroll
  for (int j = 0; j < 8; ++j) dst[lane + 64*j] = acc[j];
}

// ------------- forward FFT of two real kernel rows (radix-16 internals, round-4 proven)
//               reorder via LDS gather; M written COALESCED in base-8 digitrev order
__global__ __launch_bounds__(256,4) void k_fftkr(
    const float* __restrict__ Kr, const float* __restrict__ D, cf* __restrict__ M){
  __shared__ cf X[4096];
  const int t = threadIdx.x;
  const int h0 = blockIdx.x*2, h1 = h0 + 1;
  const float* k0p = Kr + (size_t)h0*NF;
  const float* k1p = Kr + (size_t)h1*NF;
  cf v[16];
#pragma unroll
  for (int q = 0; q < 16; ++q) v[q] = make_float2(k0p[t + 256*q], k1p[t + 256*q]);
  dft16<0>(v);
  twiddle16(v, -(PI2F/4096.0f)*(float)t);
#pragma unroll
  for (int r = 0; r < 16; ++r) X[phys16(t + 256*r)] = v[r];
  __syncthreads();
  const int base = ((t >> 4) << 8) + (t & 15);
#pragma unroll
  for (int q = 0; q < 16; ++q) v[q] = X[phys16(base + 16*q)];
  dft16<0>(v);
  twiddle16(v, -(PI2F/256.0f)*(float)(t & 15));
#pragma unroll
  for (int r = 0; r < 16; ++r) X[phys16(base + 16*r)] = v[r];
  __syncthreads();
  {
    const int s3 = t & 7;
    const float4* X4 = (const float4*)X;
#pragma unroll
    for (int j = 0; j < 8; ++j){
      float4 f = X4[8*t + (j ^ s3)];
      v[2*j]   = make_float2(f.x, f.y);
      v[2*j+1] = make_float2(f.z, f.w);
    }
  }
  dft16<0>(v);
  {
    const int s3 = t & 7;
    float4* X4 = (float4*)X;
#pragma unroll
    for (int j = 0; j < 8; ++j)
      X4[8*t + (j ^ s3)] = make_float4(v[2*j].x, v[2*j].y, v[2*j+1].x, v[2*j+1].y);
  }
  __syncthreads();
  // reorder in LDS: output slot w (base-8 digitrev, contiguous per thread),
  // true freq k = rev8(w), storage idx = base-16 digitrev of k. Coalesced stores.
  const float dd0 = D[h0*256 + h0];
  const float dd1 = D[h1*256 + h1];
  const float invN = 1.0f/4096.0f;
  float4* M0f = (float4*)(M + (size_t)h0*NF);
  float4* M1f = (float4*)(M + (size_t)h1*NF);
#pragma unroll
  for (int j = 0; j < 8; ++j){
    cf e0[2], e1[2];
#pragma unroll
    for (int s = 0; s < 2; ++s){
      int w  = 16*t + 2*j + s;
      int k  = rev8(w);
      int kc = (4096 - k) & 4095;
      int iz  = ((k  & 15) << 8) | (k  & 240) | (k  >> 8);
      int izp = ((kc & 15) << 8) | (kc & 240) | (kc >> 8);
      cf Z  = X[phys16(iz)];
      cf Zp = X[phys16(izp)];
      e0[s] = make_float2((0.5f*(Z.x + Zp.x) + dd0)*invN, 0.5f*(Z.y - Zp.y)*invN);
      e1[s] = make_float2((0.5f*(Z.y + Zp.y) + dd1)*invN, 0.5f*(Zp.x - Z.x)*invN);
    }
    M0f[8*t + j] = make_float4(e0[0].x, e0[0].y, e0[1].x, e0[1].y);
    M1f[8*t + j] = make_float4(e1[0].x, e1[0].y, e1[1].x, e1[1].y);
  }
}

// ------------- main: z = u0 + i u1 ; FFT ; *M ; IFFT ; tanh ; store ------------------
__global__ __launch_bounds__(512,8) void k_main(
    const float* __restrict__ u, const cf* __restrict__ M, float* __restrict__ out){
  __shared__ cf X[4096];                 // 32 KiB
  const int t  = threadIdx.x;
  const int h  = blockIdx.x >> 3;
  const int pr = blockIdx.x & 7;
  const size_t row0 = ((size_t)pr*256 + h)*(size_t)NF;
  const size_t row1 = row0 + (size_t)8*256*NF;
  const float* u0 = u + row0;
  const float* u1 = u + row1;
  cf v[8];
  // fwd stage 1 (span 4096)
#pragma unroll
  for (int q = 0; q < 8; ++q) v[q] = make_float2(u0[t + 512*q], u1[t + 512*q]);
  dft8<0>(v);
  twiddle8(v, -(PI2F/4096.0f)*(float)t);
#pragma unroll
  for (int r = 0; r < 8; ++r) X[physX(t + 512*r)] = v[r];
  __syncthreads();
  // fwd stage 2 (span 512)
  const int b2 = ((t >> 6) << 9) | (t & 63);
#pragma unroll
  for (int q = 0; q < 8; ++q) v[q] = X[physX(b2 + 64*q)];
  dft8<0>(v);
  twiddle8(v, -(PI2F/512.0f)*(float)(t & 63));
#pragma unroll
  for (int r = 0; r < 8; ++r) X[physX(b2 + 64*r)] = v[r];
  __syncthreads();
  // fwd stage 3 (span 64)
  const int b3 = ((t >> 3) << 6) | (t & 7);
#pragma unroll
  for (int q = 0; q < 8; ++q) v[q] = X[physX(b3 + 8*q)];
  dft8<0>(v);
  twiddle8(v, -(PI2F/64.0f)*(float)(t & 7));
#pragma unroll
  for (int r = 0; r < 8; ++r) X[physX(b3 + 8*r)] = v[r];
  __syncthreads();
  // M loads issued before stage-4 LDS reads: global latency hides under LDS+dft8
  float4 mf0, mf1;
  {
    const float4* Mr = (const float4*)(M + (size_t)h*NF + 8*t);
    mf0 = Mr[0]; mf1 = Mr[1];
  }
  // fwd stage 4 (span 8, contiguous) + pointwise + inv stage 1, in registers
#pragma unroll
  for (int q = 0; q < 8; ++q) v[q] = X[physX(8*t + q)];
  dft8<0>(v);
  {
    const float4* Mr = (const float4*)(M + (size_t)h*NF + 8*t);
    float4 f2 = Mr[2], f3 = Mr[3];
    v[0] = cmulf(v[0], make_float2(mf0.x, mf0.y));
    v[1] = cmulf(v[1], make_float2(mf0.z, mf0.w));
    v[2] = cmulf(v[2], make_float2(mf1.x, mf1.y));
    v[3] = cmulf(v[3], make_float2(mf1.z, mf1.w));
    v[4] = cmulf(v[4], make_float2(f2.x, f2.y));
    v[5] = cmulf(v[5], make_float2(f2.z, f2.w));
    v[6] = cmulf(v[6], make_float2(f3.x, f3.y));
    v[7] = cmulf(v[7], make_float2(f3.z, f3.w));
  }
  dft8<1>(v);
#pragma unroll
  for (int q = 0; q < 8; ++q) X[physX(8*t + q)] = v[q];
  __syncthreads();
  // inv stage 3
#pragma unroll
  for (int r = 0; r < 8; ++r) v[r] = X[physX(b3 + 8*r)];
  twiddle8(v, (PI2F/64.0f)*(float)(t & 7));
  dft8<1>(v);
#pragma unroll
  for (int q = 0; q < 8; ++q) X[physX(b3 + 8*q)] = v[q];
  __syncthreads();
  // inv stage 2
#pragma unroll
  for (int r = 0; r < 8; ++r) v[r] = X[physX(b2 + 64*r)];
  twiddle8(v, (PI2F/512.0f)*(float)(t & 63));
  dft8<1>(v);
#pragma unroll
  for (int q = 0; q < 8; ++q) X[physX(b2 + 64*q)] = v[q];
  __syncthreads();
  // inv stage 1 + epilogue
#pragma unroll
  for (int r = 0; r < 8; ++r) v[r] = X[physX(t + 512*r)];
  twiddle8(v, (PI2F/4096.0f)*(float)t);
  dft8<1>(v);
  float* o0 = out + row0;
  float* o1 = out + row1;
#pragma unroll
  for (int q = 0; q < 8; ++q){
    o0[t + 512*q] = fast_tanh(v[q].x);
    o1[t + 512*q] = fast_tanh(v[q].y);
  }
}

extern "C" void kernel_launch(void* const* d_in, const int* in_sizes, int n_in,
                              void* d_out, int out_size, void* d_ws, size_t ws_size,
                              hipStream_t stream){
  const float* u   = (const float*)d_in[0];
  const float* C   = (const float*)d_in[1];
  const float* D   = (const float*)d_in[2];
  const float* Bb  = (const float*)d_in[3];
  const float* Lam = (const float*)d_in[4];
  float* out = (float*)d_out;
  char* ws = (char*)d_ws;
  cf*    M    = (cf*)ws;                              // 8 MiB: [256][4096] cf, digit-rev (base 8)
  cf*    vand = (cf*)(ws + (size_t)(8u << 20));       // 2 MiB: [64][4096] cf
  float* Kr   = (float*)(ws + (size_t)(10u << 20));   // 4 MiB: [256][4096] f32

  k_vand <<<dim3(1024), dim3(256), 0, stream>>>(Lam, vand);
  k_kr   <<<dim3(256),  dim3(512), 0, stream>>>(C, Bb, vand, Kr);
  k_fftkr<<<dim3(128),  dim3(256), 0, stream>>>(Kr, D, M);
  k_main <<<dim3(2048), dim3(512), 0, stream>>>(u, M, out);
}

// Round 8
// 72.309 us; speedup vs baseline: 1.2234x; 1.2234x over previous
//
#include <hip/hip_runtime.h>
#include <cmath>

#define NF 4096
#define PI2F 6.2831853071795864769f

typedef float2 cf;

__device__ __forceinline__ cf cmulf(cf a, cf b){
  return make_float2(fmaf(a.x, b.x, -(a.y*b.y)), fmaf(a.x, b.y, a.y*b.x));
}
__device__ __forceinline__ cf cadd(cf a, cf b){ return make_float2(a.x+b.x, a.y+b.y); }
__device__ __forceinline__ cf csub(cf a, cf b){ return make_float2(a.x-b.x, a.y-b.y); }

// ---- k_main LDS map: additive pad (PROVEN 52us config, rounds 5+6) ----
__device__ __forceinline__ int phys8(int i){ return i + (i >> 3); }
// ---- k_fftkr LDS map: pair-preserving XOR (radix-16 path, round-4 proven) ----
__device__ __forceinline__ int phys16(int i){ return i ^ (((i >> 4) & 7) << 1); }

// base-8 digit reversal of a 12-bit index (involution)
__device__ __forceinline__ int rev8(int i){
  return ((i & 7) << 9) | (((i >> 3) & 7) << 6) | (((i >> 6) & 7) << 3) | ((i >> 9) & 7);
}

// radix-8 DFT in registers; INV=0 forward (e^{-i}), INV=1 inverse (e^{+i}), unnormalized.
template<int INV>
__device__ __forceinline__ void dft8(cf* v){
  const float HF = 0.7071067811865476f;
  cf e0,e1,e2,e3,o0,o1,o2,o3;
  {
    cf t0 = cadd(v[0], v[4]);
    cf t1 = csub(v[0], v[4]);
    cf t2 = cadd(v[2], v[6]);
    cf t3 = csub(v[2], v[6]);
    e0 = cadd(t0,t2); e2 = csub(t0,t2);
    if (!INV){ e1 = make_float2(t1.x+t3.y, t1.y-t3.x); e3 = make_float2(t1.x-t3.y, t1.y+t3.x); }
    else     { e1 = make_float2(t1.x-t3.y, t1.y+t3.x); e3 = make_float2(t1.x+t3.y, t1.y-t3.x); }
  }
  {
    cf t0 = cadd(v[1], v[5]);
    cf t1 = csub(v[1], v[5]);
    cf t2 = cadd(v[3], v[7]);
    cf t3 = csub(v[3], v[7]);
    o0 = cadd(t0,t2); o2 = csub(t0,t2);
    if (!INV){ o1 = make_float2(t1.x+t3.y, t1.y-t3.x); o3 = make_float2(t1.x-t3.y, t1.y+t3.x); }
    else     { o1 = make_float2(t1.x-t3.y, t1.y+t3.x); o3 = make_float2(t1.x+t3.y, t1.y-t3.x); }
  }
  cf w1, w2, w3;
  if (!INV){
    w1 = make_float2(HF*(o1.x + o1.y), HF*(o1.y - o1.x));
    w2 = make_float2(o2.y, -o2.x);
    w3 = make_float2(HF*(o3.y - o3.x), -HF*(o3.x + o3.y));
  } else {
    w1 = make_float2(HF*(o1.x - o1.y), HF*(o1.y + o1.x));
    w2 = make_float2(-o2.y, o2.x);
    w3 = make_float2(-HF*(o3.x + o3.y), HF*(o3.x - o3.y));
  }
  v[0] = cadd(e0,o0); v[4] = csub(e0,o0);
  v[1] = cadd(e1,w1); v[5] = csub(e1,w1);
  v[2] = cadd(e2,w2); v[6] = csub(e2,w2);
  v[3] = cadd(e3,w3); v[7] = csub(e3,w3);
}

// radix-16 DFT in registers (k_fftkr path)
template<int INV>
__device__ __forceinline__ void dft16(cf* v){
  const float C1 = 0.9238795325112867f;
  const float S1 = 0.3826834323650898f;
  const float HF = 0.7071067811865476f;
  cf c[16];
#pragma unroll
  for (int q1 = 0; q1 < 4; ++q1){
    cf a = v[q1], b = v[q1+4], d = v[q1+8], e = v[q1+12];
    cf t0 = make_float2(a.x+d.x, a.y+d.y);
    cf t1 = make_float2(a.x-d.x, a.y-d.y);
    cf t2 = make_float2(b.x+e.x, b.y+e.y);
    cf t3 = make_float2(b.x-e.x, b.y-e.y);
    c[q1*4+0] = make_float2(t0.x+t2.x, t0.y+t2.y);
    c[q1*4+2] = make_float2(t0.x-t2.x, t0.y-t2.y);
    if (!INV){
      c[q1*4+1] = make_float2(t1.x+t3.y, t1.y-t3.x);
      c[q1*4+3] = make_float2(t1.x-t3.y, t1.y+t3.x);
    } else {
      c[q1*4+1] = make_float2(t1.x-t3.y, t1.y+t3.x);
      c[q1*4+3] = make_float2(t1.x+t3.y, t1.y-t3.x);
    }
  }
  {
    auto tw = [&](int i, float wr, float wi){
      float wii = INV ? -wi : wi;
      cf z = c[i];
      c[i] = make_float2(fmaf(z.x, wr, -(z.y*wii)), fmaf(z.x, wii, z.y*wr));
    };
    tw(5,  C1, -S1);
    tw(6,  HF, -HF);
    tw(7,  S1, -C1);
    tw(9,  HF, -HF);
    tw(11,-HF, -HF);
    tw(13, S1, -C1);
    tw(14,-HF, -HF);
    tw(15,-C1,  S1);
    cf z = c[10];
    c[10] = INV ? make_float2(-z.y, z.x) : make_float2(z.y, -z.x);
  }
#pragma unroll
  for (int r0 = 0; r0 < 4; ++r0){
    cf a = c[r0], b = c[4+r0], d = c[8+r0], e = c[12+r0];
    cf t0 = make_float2(a.x+d.x, a.y+d.y);
    cf t1 = make_float2(a.x-d.x, a.y-d.y);
    cf t2 = make_float2(b.x+e.x, b.y+e.y);
    cf t3 = make_float2(b.x-e.x, b.y-e.y);
    v[r0+0] = make_float2(t0.x+t2.x, t0.y+t2.y);
    v[r0+8] = make_float2(t0.x-t2.x, t0.y-t2.y);
    if (!INV){
      v[r0+4]  = make_float2(t1.x+t3.y, t1.y-t3.x);
      v[r0+12] = make_float2(t1.x-t3.y, t1.y+t3.x);
    } else {
      v[r0+4]  = make_float2(t1.x-t3.y, t1.y+t3.x);
      v[r0+12] = make_float2(t1.x+t3.y, t1.y-t3.x);
    }
  }
}

// v[r] *= e^{i*ang*r}, r=1..7. Chebyshev power build: T_{r+1} = 2c*T_r - T_{r-1}
__device__ __forceinline__ void twiddle8(cf* v, float ang){
  float s, c;
  __sincosf(ang, &s, &c);
  float c2 = 2.0f * c;
  cf T[8];
  T[1] = make_float2(c, s);
  T[2] = make_float2(fmaf(c2, c, -1.0f), c2 * s);
#pragma unroll
  for (int r = 3; r < 8; ++r)
    T[r] = make_float2(fmaf(c2, T[r-1].x, -T[r-2].x), fmaf(c2, T[r-1].y, -T[r-2].y));
#pragma unroll
  for (int r = 1; r < 8; ++r) v[r] = cmulf(v[r], T[r]);
}

// v[r] *= e^{i*ang*r}, r=1..15 (radix-16 path), Chebyshev build
__device__ __forceinline__ void twiddle16(cf* v, float ang){
  float s, c;
  __sincosf(ang, &s, &c);
  float c2 = 2.0f * c;
  cf T[16];
  T[1] = make_float2(c, s);
  T[2] = make_float2(fmaf(c2, c, -1.0f), c2 * s);
#pragma unroll
  for (int r = 3; r < 16; ++r)
    T[r] = make_float2(fmaf(c2, T[r-1].x, -T[r-2].x), fmaf(c2, T[r-1].y, -T[r-2].y));
#pragma unroll
  for (int r = 1; r < 16; ++r) v[r] = cmulf(v[r], T[r]);
}

__device__ __forceinline__ float fast_tanh(float x){
  float e = __expf(2.0f*x);
  return 1.0f - __fdividef(2.0f, e + 1.0f);
}

// ---------------- vandermonde: vand[p][l] = lambda_p^l (polar, f64 phase) -------------
__global__ void k_vand(const float* __restrict__ Lam, cf* __restrict__ vand){
  int gid = blockIdx.x*256 + threadIdx.x;        // 64*4096
  int p = gid >> 12;
  int l = gid & 4095;
  float lr = Lam[2*p], li = Lam[2*p+1];
  double r2 = (double)lr*(double)lr + (double)li*(double)li;
  double lg = 0.5 * log2(r2);                    // log2|lambda|
  double tt = atan2((double)li, (double)lr) * 0.15915494309189535; // turns
  double dl = (double)l;
  float mag = exp2f((float)(dl * lg));
  double ph = dl * tt;
  ph -= floor(ph);                               // frac turns in [0,1)
  float s, c;
  sincospif((float)(2.0*ph), &s, &c);
  vand[gid] = make_float2(mag*c, mag*s);
}

// ---------------- Kr[h][l] = Re( sum_p C[h,p]*B[p,h] * vand[p][l] ) -------------------
__global__ __launch_bounds__(512,4) void k_kr(
    const float* __restrict__ C, const float* __restrict__ Bb,
    const cf* __restrict__ vand, float* __restrict__ Kr){
  __shared__ cf Wsh[8][64];
  __shared__ cf Vt[16][512];     // 64 KiB tile
  const int t = threadIdx.x;
  const int hg = blockIdx.x >> 3;      // 32 h-groups of 8
  const int ls = blockIdx.x & 7;       // 8 l-slices of 512
  const int h0 = hg*8;
  const int l0 = ls*512;
  {
    int hl = t >> 6, p = t & 63;       // 512 entries
    int h = h0 + hl;
    cf cc = ((const cf*)C)[h*64 + p];
    cf bb = ((const cf*)Bb)[p*256 + h];
    Wsh[hl][p] = cmulf(cc, bb);
  }
  float acc[8] = {0,0,0,0,0,0,0,0};
  const int hl = t >> 6;               // wave id == local h
  const int lane = t & 63;
  for (int pc = 0; pc < 4; ++pc){
    __syncthreads();
    const float4* src = (const float4*)vand;  // row stride 2048 float4
#pragma unroll
    for (int j = 0; j < 8; ++j){
      int li = j*512 + t;              // 0..4095 float4s of tile
      int rp = li >> 8;                // tile row 0..15
      int colf4 = li & 255;
      ((float4*)Vt)[li] = src[(size_t)(pc*16 + rp)*2048 + (l0 >> 1) + colf4];
    }
    __syncthreads();
#pragma unroll
    for (int p = 0; p < 16; ++p){
      cf w = Wsh[hl][pc*16 + p];
#pragma unroll
      for (int j = 0; j < 8; ++j){
        cf vv = Vt[p][lane + 64*j];
        acc[j] = fmaf(w.x, vv.x, fmaf(-w.y, vv.y, acc[j]));
      }
    }
  }
  float* dst = Kr + (size_t)(h0 + hl)*NF + l0;
#pragma unroll
  for (int j = 0; j < 8; ++j) dst[lane + 64*j] = acc[j];
}

// ------------- forward FFT of two real kernel rows (radix-16 internals, round-4 proven)
//               reorder via LDS gather; M written COALESCED in base-8 digitrev order
__global__ __launch_bounds__(256,4) void k_fftkr(
    const float* __restrict__ Kr, const float* __restrict__ D, cf* __restrict__ M){
  __shared__ cf X[4096];
  const int t = threadIdx.x;
  const int h0 = blockIdx.x*2, h1 = h0 + 1;
  const float* k0p = Kr + (size_t)h0*NF;
  const float* k1p = Kr + (size_t)h1*NF;
  cf v[16];
#pragma unroll
  for (int q = 0; q < 16; ++q) v[q] = make_float2(k0p[t + 256*q], k1p[t + 256*q]);
  dft16<0>(v);
  twiddle16(v, -(PI2F/4096.0f)*(float)t);
#pragma unroll
  for (int r = 0; r < 16; ++r) X[phys16(t + 256*r)] = v[r];
  __syncthreads();
  const int base = ((t >> 4) << 8) + (t & 15);
#pragma unroll
  for (int q = 0; q < 16; ++q) v[q] = X[phys16(base + 16*q)];
  dft16<0>(v);
  twiddle16(v, -(PI2F/256.0f)*(float)(t & 15));
#pragma unroll
  for (int r = 0; r < 16; ++r) X[phys16(base + 16*r)] = v[r];
  __syncthreads();
  {
    const int s3 = t & 7;
    const float4* X4 = (const float4*)X;
#pragma unroll
    for (int j = 0; j < 8; ++j){
      float4 f = X4[8*t + (j ^ s3)];
      v[2*j]   = make_float2(f.x, f.y);
      v[2*j+1] = make_float2(f.z, f.w);
    }
  }
  dft16<0>(v);
  {
    const int s3 = t & 7;
    float4* X4 = (float4*)X;
#pragma unroll
    for (int j = 0; j < 8; ++j)
      X4[8*t + (j ^ s3)] = make_float4(v[2*j].x, v[2*j].y, v[2*j+1].x, v[2*j+1].y);
  }
  __syncthreads();
  // reorder in LDS: output slot w (base-8 digitrev, contiguous per thread),
  // true freq k = rev8(w), storage idx = base-16 digitrev of k. Coalesced stores.
  const float dd0 = D[h0*256 + h0];
  const float dd1 = D[h1*256 + h1];
  const float invN = 1.0f/4096.0f;
  float4* M0f = (float4*)(M + (size_t)h0*NF);
  float4* M1f = (float4*)(M + (size_t)h1*NF);
#pragma unroll
  for (int j = 0; j < 8; ++j){
    cf e0[2], e1[2];
#pragma unroll
    for (int s = 0; s < 2; ++s){
      int w  = 16*t + 2*j + s;
      int k  = rev8(w);
      int kc = (4096 - k) & 4095;
      int iz  = ((k  & 15) << 8) | (k  & 240) | (k  >> 8);
      int izp = ((kc & 15) << 8) | (kc & 240) | (kc >> 8);
      cf Z  = X[phys16(iz)];
      cf Zp = X[phys16(izp)];
      e0[s] = make_float2((0.5f*(Z.x + Zp.x) + dd0)*invN, 0.5f*(Z.y - Zp.y)*invN);
      e1[s] = make_float2((0.5f*(Z.y + Zp.y) + dd1)*invN, 0.5f*(Zp.x - Z.x)*invN);
    }
    M0f[8*t + j] = make_float4(e0[0].x, e0[0].y, e0[1].x, e0[1].y);
    M1f[8*t + j] = make_float4(e1[0].x, e1[0].y, e1[1].x, e1[1].y);
  }
}

// ------------- main: z = u0 + i u1 ; FFT ; *M ; IFFT ; tanh ; store ------------------
// PROVEN round-5/6 configuration: phys8 additive pad, 36 KiB LDS. Do not touch.
__global__ __launch_bounds__(512,8) void k_main(
    const float* __restrict__ u, const cf* __restrict__ M, float* __restrict__ out){
  __shared__ cf X[4608];                 // 36 KiB
  const int t  = threadIdx.x;
  const int h  = blockIdx.x >> 3;
  const int pr = blockIdx.x & 7;
  const size_t row0 = ((size_t)pr*256 + h)*(size_t)NF;
  const size_t row1 = row0 + (size_t)8*256*NF;
  const float* u0 = u + row0;
  const float* u1 = u + row1;
  cf v[8];
  // fwd stage 1 (span 4096)
#pragma unroll
  for (int q = 0; q < 8; ++q) v[q] = make_float2(u0[t + 512*q], u1[t + 512*q]);
  dft8<0>(v);
  twiddle8(v, -(PI2F/4096.0f)*(float)t);
#pragma unroll
  for (int r = 0; r < 8; ++r) X[phys8(t + 512*r)] = v[r];
  __syncthreads();
  // fwd stage 2 (span 512)
  const int b2 = ((t >> 6) << 9) | (t & 63);
#pragma unroll
  for (int q = 0; q < 8; ++q) v[q] = X[phys8(b2 + 64*q)];
  dft8<0>(v);
  twiddle8(v, -(PI2F/512.0f)*(float)(t & 63));
#pragma unroll
  for (int r = 0; r < 8; ++r) X[phys8(b2 + 64*r)] = v[r];
  __syncthreads();
  // fwd stage 3 (span 64)
  const int b3 = ((t >> 3) << 6) | (t & 7);
#pragma unroll
  for (int q = 0; q < 8; ++q) v[q] = X[phys8(b3 + 8*q)];
  dft8<0>(v);
  twiddle8(v, -(PI2F/64.0f)*(float)(t & 7));
#pragma unroll
  for (int r = 0; r < 8; ++r) X[phys8(b3 + 8*r)] = v[r];
  __syncthreads();
  // M loads issued before stage-4 LDS reads: global latency hides under LDS+dft8
  float4 mf0, mf1;
  {
    const float4* Mr = (const float4*)(M + (size_t)h*NF + 8*t);
    mf0 = Mr[0]; mf1 = Mr[1];
  }
  // fwd stage 4 (span 8, contiguous) + pointwise + inv stage 1, in registers
#pragma unroll
  for (int q = 0; q < 8; ++q) v[q] = X[phys8(8*t + q)];
  dft8<0>(v);
  {
    const float4* Mr = (const float4*)(M + (size_t)h*NF + 8*t);
    float4 f2 = Mr[2], f3 = Mr[3];
    v[0] = cmulf(v[0], make_float2(mf0.x, mf0.y));
    v[1] = cmulf(v[1], make_float2(mf0.z, mf0.w));
    v[2] = cmulf(v[2], make_float2(mf1.x, mf1.y));
    v[3] = cmulf(v[3], make_float2(mf1.z, mf1.w));
    v[4] = cmulf(v[4], make_float2(f2.x, f2.y));
    v[5] = cmulf(v[5], make_float2(f2.z, f2.w));
    v[6] = cmulf(v[6], make_float2(f3.x, f3.y));
    v[7] = cmulf(v[7], make_float2(f3.z, f3.w));
  }
  dft8<1>(v);
#pragma unroll
  for (int q = 0; q < 8; ++q) X[phys8(8*t + q)] = v[q];
  __syncthreads();
  // inv stage 3
#pragma unroll
  for (int r = 0; r < 8; ++r) v[r] = X[phys8(b3 + 8*r)];
  twiddle8(v, (PI2F/64.0f)*(float)(t & 7));
  dft8<1>(v);
#pragma unroll
  for (int q = 0; q < 8; ++q) X[phys8(b3 + 8*q)] = v[q];
  __syncthreads();
  // inv stage 2
#pragma unroll
  for (int r = 0; r < 8; ++r) v[r] = X[phys8(b2 + 64*r)];
  twiddle8(v, (PI2F/512.0f)*(float)(t & 63));
  dft8<1>(v);
#pragma unroll
  for (int q = 0; q < 8; ++q) X[phys8(b2 + 64*q)] = v[q];
  __syncthreads();
  // inv stage 1 + epilogue
#pragma unroll
  for (int r = 0; r < 8; ++r) v[r] = X[phys8(t + 512*r)];
  twiddle8(v, (PI2F/4096.0f)*(float)t);
  dft8<1>(v);
  float* o0 = out + row0;
  float* o1 = out + row1;
#pragma unroll
  for (int q = 0; q < 8; ++q){
    o0[t + 512*q] = fast_tanh(v[q].x);
    o1[t + 512*q] = fast_tanh(v[q].y);
  }
}

extern "C" void kernel_launch(void* const* d_in, const int* in_sizes, int n_in,
                              void* d_out, int out_size, void* d_ws, size_t ws_size,
                              hipStream_t stream){
  const float* u   = (const float*)d_in[0];
  const float* C   = (const float*)d_in[1];
  const float* D   = (const float*)d_in[2];
  const float* Bb  = (const float*)d_in[3];
  const float* Lam = (const float*)d_in[4];
  float* out = (float*)d_out;
  char* ws = (char*)d_ws;
  cf*    M    = (cf*)ws;                              // 8 MiB: [256][4096] cf, digit-rev (base 8)
  cf*    vand = (cf*)(ws + (size_t)(8u << 20));       // 2 MiB: [64][4096] cf
  float* Kr   = (float*)(ws + (size_t)(10u << 20));   // 4 MiB: [256][4096] f32

  k_vand <<<dim3(1024), dim3(256), 0, stream>>>(Lam, vand);
  k_kr   <<<dim3(256),  dim3(512), 0, stream>>>(C, Bb, vand, Kr);
  k_fftkr<<<dim3(128),  dim3(256), 0, stream>>>(Kr, D, M);
  k_main <<<dim3(2048), dim3(512), 0, stream>>>(u, M, out);
}

// Round 9
// 64.044 us; speedup vs baseline: 1.3813x; 1.1291x over previous
//
#include <hip/hip_runtime.h>
#include <cmath>

#define NF 4096
#define PI2F 6.2831853071795864769f

typedef float2 cf;

__device__ __forceinline__ cf cmulf(cf a, cf b){
  return make_float2(fmaf(a.x, b.x, -(a.y*b.y)), fmaf(a.x, b.y, a.y*b.x));
}
__device__ __forceinline__ cf cadd(cf a, cf b){ return make_float2(a.x+b.x, a.y+b.y); }
__device__ __forceinline__ cf csub(cf a, cf b){ return make_float2(a.x-b.x, a.y-b.y); }

// ---- k_main LDS map: additive pad (PROVEN 52us config, rounds 5+6+8) ----
__device__ __forceinline__ int phys8(int i){ return i + (i >> 3); }

// base-8 digit reversal of a 12-bit index (involution): slot w <-> true freq k
__device__ __forceinline__ int rev8(int i){
  return ((i & 7) << 9) | (((i >> 3) & 7) << 6) | (((i >> 6) & 7) << 3) | ((i >> 9) & 7);
}

// radix-8 DFT in registers; INV=0 forward (e^{-i}), INV=1 inverse (e^{+i}), unnormalized.
template<int INV>
__device__ __forceinline__ void dft8(cf* v){
  const float HF = 0.7071067811865476f;
  cf e0,e1,e2,e3,o0,o1,o2,o3;
  {
    cf t0 = cadd(v[0], v[4]);
    cf t1 = csub(v[0], v[4]);
    cf t2 = cadd(v[2], v[6]);
    cf t3 = csub(v[2], v[6]);
    e0 = cadd(t0,t2); e2 = csub(t0,t2);
    if (!INV){ e1 = make_float2(t1.x+t3.y, t1.y-t3.x); e3 = make_float2(t1.x-t3.y, t1.y+t3.x); }
    else     { e1 = make_float2(t1.x-t3.y, t1.y+t3.x); e3 = make_float2(t1.x+t3.y, t1.y-t3.x); }
  }
  {
    cf t0 = cadd(v[1], v[5]);
    cf t1 = csub(v[1], v[5]);
    cf t2 = cadd(v[3], v[7]);
    cf t3 = csub(v[3], v[7]);
    o0 = cadd(t0,t2); o2 = csub(t0,t2);
    if (!INV){ o1 = make_float2(t1.x+t3.y, t1.y-t3.x); o3 = make_float2(t1.x-t3.y, t1.y+t3.x); }
    else     { o1 = make_float2(t1.x-t3.y, t1.y+t3.x); o3 = make_float2(t1.x+t3.y, t1.y-t3.x); }
  }
  cf w1, w2, w3;
  if (!INV){
    w1 = make_float2(HF*(o1.x + o1.y), HF*(o1.y - o1.x));
    w2 = make_float2(o2.y, -o2.x);
    w3 = make_float2(HF*(o3.y - o3.x), -HF*(o3.x + o3.y));
  } else {
    w1 = make_float2(HF*(o1.x - o1.y), HF*(o1.y + o1.x));
    w2 = make_float2(-o2.y, o2.x);
    w3 = make_float2(-HF*(o3.x + o3.y), HF*(o3.x - o3.y));
  }
  v[0] = cadd(e0,o0); v[4] = csub(e0,o0);
  v[1] = cadd(e1,w1); v[5] = csub(e1,w1);
  v[2] = cadd(e2,w2); v[6] = csub(e2,w2);
  v[3] = cadd(e3,w3); v[7] = csub(e3,w3);
}

// v[r] *= e^{i*ang*r}, r=1..7. Chebyshev power build: T_{r+1} = 2c*T_r - T_{r-1}
__device__ __forceinline__ void twiddle8(cf* v, float ang){
  float s, c;
  __sincosf(ang, &s, &c);
  float c2 = 2.0f * c;
  cf T[8];
  T[1] = make_float2(c, s);
  T[2] = make_float2(fmaf(c2, c, -1.0f), c2 * s);
#pragma unroll
  for (int r = 3; r < 8; ++r)
    T[r] = make_float2(fmaf(c2, T[r-1].x, -T[r-2].x), fmaf(c2, T[r-1].y, -T[r-2].y));
#pragma unroll
  for (int r = 1; r < 8; ++r) v[r] = cmulf(v[r], T[r]);
}

__device__ __forceinline__ float fast_tanh(float x){
  float e = __expf(2.0f*x);
  return 1.0f - __fdividef(2.0f, e + 1.0f);
}

// ---------------- k_geo: closed-form spectral tables, f64 exact --------------------
// For slot w (tab stored in k_main's base-8 digitrev order), true freq k = rev8(w):
//   G1 = (1-lam^N)/(1-lam*cis(-2pi k/N)),  G2 = (1-lam^N)/(1-lam*cis(+2pi k/N)) [= G at N-k]
//   A  = (G1 + conj(G2))/2 / N             (multiplies Re(W))
//   B2 = i*(G1 - conj(G2))/2 / N           (multiplies Im(W))
// tab[p][w] = (A.r, A.i, B2.r, B2.i)
__global__ void k_geo(const float* __restrict__ Lam, float4* __restrict__ tab){
  int gid = blockIdx.x*256 + threadIdx.x;       // 64*4096
  int p = gid >> 12;
  int w = gid & 4095;
  int k = rev8(w);
  double lr = (double)Lam[2*p], li = (double)Lam[2*p+1];
  double r2 = lr*lr + li*li;
  double r  = sqrt(r2);
  double tt = atan2(li, lr) * 0.15915494309189535;   // phase in turns
  // lambda^N (N=4096), f64 polar with frac-turn range reduction
  double rN = exp2(4096.0 * (0.5 * log2(r2)));
  double pN = 4096.0 * tt;
  pN -= floor(pN);
  double sN, cN;
  sincospi(2.0*pN, &sN, &cN);
  double numr = 1.0 - rN*cN;
  double numi =     - rN*sN;
  // G1: denom = 1 - r*cis(2pi*(tt - k/N))
  double ph1 = tt - (double)k * (1.0/4096.0);
  double s1, c1; sincospi(2.0*ph1, &s1, &c1);
  double d1r = 1.0 - r*c1, d1i = -r*s1;
  double inv1 = 1.0/(d1r*d1r + d1i*d1i);
  double g1r = (numr*d1r + numi*d1i)*inv1;
  double g1i = (numi*d1r - numr*d1i)*inv1;
  // G2: denom = 1 - r*cis(2pi*(tt + k/N))
  double ph2 = tt + (double)k * (1.0/4096.0);
  double s2, c2; sincospi(2.0*ph2, &s2, &c2);
  double d2r = 1.0 - r*c2, d2i = -r*s2;
  double inv2 = 1.0/(d2r*d2r + d2i*d2i);
  double g2r = (numr*d2r + numi*d2i)*inv2;
  double g2i = (numi*d2r - numr*d2i)*inv2;
  const double hN = 0.5/4096.0;
  double Ar  =  (g1r + g2r)*hN, Ai  = (g1i - g2i)*hN;
  double B2r = -(g1i + g2i)*hN, B2i = (g1r - g2r)*hN;
  tab[(size_t)p*4096 + w] = make_float4((float)Ar, (float)Ai, (float)B2r, (float)B2i);
}

// ---------------- k_red: M[h][w] = sum_p Wr*A + Wi*B2  (+ dd/N on real) ------------
// block: 512 thr = 8 waves x 4 h each -> h-group 32; k-slice 128; grid 8x32 = 256.
__global__ __launch_bounds__(512,4) void k_red(
    const float* __restrict__ C, const float* __restrict__ Bb,
    const float4* __restrict__ tab, const float* __restrict__ D,
    cf* __restrict__ M){
  __shared__ cf Wsh[32][64];          // 16 KiB
  __shared__ float4 Tt[8][128];       // 16 KiB
  const int t  = threadIdx.x;
  const int hg = blockIdx.x >> 5;     // 0..7
  const int ls = blockIdx.x & 31;     // 0..31
  const int h0 = hg*32;
  const int w0 = ls*128;
  // stage W = C[h,p]*Bb[p,h]: 2048 entries, 4 per thread
#pragma unroll
  for (int e = 0; e < 4; ++e){
    int idx = e*512 + t;
    int hl = idx >> 6, p = idx & 63;
    int h = h0 + hl;
    cf cc = ((const cf*)C)[h*64 + p];
    cf bb = ((const cf*)Bb)[p*256 + h];
    Wsh[hl][p] = cmulf(cc, bb);
  }
  const int wave = t >> 6;
  const int lane = t & 63;
  const int hh = wave*4;              // this wave's 4 local h
  float accr[2][4] = {{0,0,0,0},{0,0,0,0}};
  float acci[2][4] = {{0,0,0,0},{0,0,0,0}};
  for (int pc = 0; pc < 8; ++pc){
    __syncthreads();
#pragma unroll
    for (int e = 0; e < 2; ++e){
      int idx = e*512 + t;            // 1024 float4 tile entries
      int row = idx >> 7, col = idx & 127;
      Tt[row][col] = tab[(size_t)(pc*8 + row)*4096 + w0 + col];
    }
    __syncthreads();
#pragma unroll
    for (int p = 0; p < 8; ++p){
      cf Wc[4];
#pragma unroll
      for (int h = 0; h < 4; ++h) Wc[h] = Wsh[hh + h][pc*8 + p];   // broadcast
#pragma unroll
      for (int j = 0; j < 2; ++j){
        float4 f = Tt[p][lane + 64*j];
#pragma unroll
        for (int h = 0; h < 4; ++h){
          accr[j][h] = fmaf(Wc[h].x, f.x, fmaf(Wc[h].y, f.z, accr[j][h]));
          acci[j][h] = fmaf(Wc[h].x, f.y, fmaf(Wc[h].y, f.w, acci[j][h]));
        }
      }
    }
  }
  const float invN = 1.0f/4096.0f;
#pragma unroll
  for (int h = 0; h < 4; ++h){
    int hq = h0 + hh + h;
    float dd = D[hq*256 + hq] * invN;
#pragma unroll
    for (int j = 0; j < 2; ++j)
      M[(size_t)hq*NF + w0 + lane + 64*j] = make_float2(accr[j][h] + dd, acci[j][h]);
  }
}

// ------------- main: z = u0 + i u1 ; FFT ; *M ; IFFT ; tanh ; store ------------------
// PROVEN round-5/6/8 configuration: phys8 additive pad, 36 KiB LDS. Untouched.
__global__ __launch_bounds__(512,8) void k_main(
    const float* __restrict__ u, const cf* __restrict__ M, float* __restrict__ out){
  __shared__ cf X[4608];                 // 36 KiB
  const int t  = threadIdx.x;
  const int h  = blockIdx.x >> 3;
  const int pr = blockIdx.x & 7;
  const size_t row0 = ((size_t)pr*256 + h)*(size_t)NF;
  const size_t row1 = row0 + (size_t)8*256*NF;
  const float* u0 = u + row0;
  const float* u1 = u + row1;
  cf v[8];
  // fwd stage 1 (span 4096)
#pragma unroll
  for (int q = 0; q < 8; ++q) v[q] = make_float2(u0[t + 512*q], u1[t + 512*q]);
  dft8<0>(v);
  twiddle8(v, -(PI2F/4096.0f)*(float)t);
#pragma unroll
  for (int r = 0; r < 8; ++r) X[phys8(t + 512*r)] = v[r];
  __syncthreads();
  // fwd stage 2 (span 512)
  const int b2 = ((t >> 6) << 9) | (t & 63);
#pragma unroll
  for (int q = 0; q < 8; ++q) v[q] = X[phys8(b2 + 64*q)];
  dft8<0>(v);
  twiddle8(v, -(PI2F/512.0f)*(float)(t & 63));
#pragma unroll
  for (int r = 0; r < 8; ++r) X[phys8(b2 + 64*r)] = v[r];
  __syncthreads();
  // fwd stage 3 (span 64)
  const int b3 = ((t >> 3) << 6) | (t & 7);
#pragma unroll
  for (int q = 0; q < 8; ++q) v[q] = X[phys8(b3 + 8*q)];
  dft8<0>(v);
  twiddle8(v, -(PI2F/64.0f)*(float)(t & 7));
#pragma unroll
  for (int r = 0; r < 8; ++r) X[phys8(b3 + 8*r)] = v[r];
  __syncthreads();
  // M loads issued before stage-4 LDS reads: global latency hides under LDS+dft8
  float4 mf0, mf1;
  {
    const float4* Mr = (const float4*)(M + (size_t)h*NF + 8*t);
    mf0 = Mr[0]; mf1 = Mr[1];
  }
  // fwd stage 4 (span 8, contiguous) + pointwise + inv stage 1, in registers
#pragma unroll
  for (int q = 0; q < 8; ++q) v[q] = X[phys8(8*t + q)];
  dft8<0>(v);
  {
    const float4* Mr = (const float4*)(M + (size_t)h*NF + 8*t);
    float4 f2 = Mr[2], f3 = Mr[3];
    v[0] = cmulf(v[0], make_float2(mf0.x, mf0.y));
    v[1] = cmulf(v[1], make_float2(mf0.z, mf0.w));
    v[2] = cmulf(v[2], make_float2(mf1.x, mf1.y));
    v[3] = cmulf(v[3], make_float2(mf1.z, mf1.w));
    v[4] = cmulf(v[4], make_float2(f2.x, f2.y));
    v[5] = cmulf(v[5], make_float2(f2.z, f2.w));
    v[6] = cmulf(v[6], make_float2(f3.x, f3.y));
    v[7] = cmulf(v[7], make_float2(f3.z, f3.w));
  }
  dft8<1>(v);
#pragma unroll
  for (int q = 0; q < 8; ++q) X[phys8(8*t + q)] = v[q];
  __syncthreads();
  // inv stage 3
#pragma unroll
  for (int r = 0; r < 8; ++r) v[r] = X[phys8(b3 + 8*r)];
  twiddle8(v, (PI2F/64.0f)*(float)(t & 7));
  dft8<1>(v);
#pragma unroll
  for (int q = 0; q < 8; ++q) X[phys8(b3 + 8*q)] = v[q];
  __syncthreads();
  // inv stage 2
#pragma unroll
  for (int r = 0; r < 8; ++r) v[r] = X[phys8(b2 + 64*r)];
  twiddle8(v, (PI2F/512.0f)*(float)(t & 63));
  dft8<1>(v);
#pragma unroll
  for (int q = 0; q < 8; ++q) X[phys8(b2 + 64*q)] = v[q];
  __syncthreads();
  // inv stage 1 + epilogue
#pragma unroll
  for (int r = 0; r < 8; ++r) v[r] = X[phys8(t + 512*r)];
  twiddle8(v, (PI2F/4096.0f)*(float)t);
  dft8<1>(v);
  float* o0 = out + row0;
  float* o1 = out + row1;
#pragma unroll
  for (int q = 0; q < 8; ++q){
    o0[t + 512*q] = fast_tanh(v[q].x);
    o1[t + 512*q] = fast_tanh(v[q].y);
  }
}

extern "C" void kernel_launch(void* const* d_in, const int* in_sizes, int n_in,
                              void* d_out, int out_size, void* d_ws, size_t ws_size,
                              hipStream_t stream){
  const float* u   = (const float*)d_in[0];
  const float* C   = (const float*)d_in[1];
  const float* D   = (const float*)d_in[2];
  const float* Bb  = (const float*)d_in[3];
  const float* Lam = (const float*)d_in[4];
  float* out = (float*)d_out;
  char* ws = (char*)d_ws;
  cf*     M   = (cf*)ws;                              // 8 MiB: [256][4096] cf, rev8 slot order
  float4* tab = (float4*)(ws + (size_t)(8u << 20));   // 4 MiB: [64][4096] float4 (A, iB)

  k_geo <<<dim3(1024), dim3(256), 0, stream>>>(Lam, tab);
  k_red <<<dim3(256),  dim3(512), 0, stream>>>(C, Bb, tab, D, M);
  k_main<<<dim3(2048), dim3(512), 0, stream>>>(u, M, out);
}